// Round 6
// baseline (974.605 us; speedup 1.0000x reference)
//
#include <hip/hip_runtime.h>

// MoE top-2 of 8 experts. B=4096 tokens, D=1024, H=4096.
// Round 9: weight transpose+convert FUSED into the GEMM B-staging.
// B is read [k][n] fp32 directly from W1/W2, converted to bf16 in regs
// (prefetched one K-step ahead), ds_write'd into the SAME [n][32]-short
// LDS layout the proven round-0 fragment reads use. A-path and the
// 2-barrier 128x128 BK=32 structure are unchanged. The 4 transpose
// dispatches and the wt buffer are deleted.

typedef __attribute__((ext_vector_type(8))) short short8;
typedef __attribute__((ext_vector_type(4))) float f32x4;

#define B_TOK 4096
#define D_DIM 1024
#define H_DIM 4096
#define N_EXP 8
#define H_HALF 2048

__device__ __forceinline__ unsigned short f2bf(float f) {
  unsigned int u = __float_as_uint(f);
  u += 0x7fffu + ((u >> 16) & 1u);  // RNE
  return (unsigned short)(u >> 16);
}
__device__ __forceinline__ float bf2f(unsigned short s) {
  return __uint_as_float(((unsigned int)s) << 16);
}
__device__ __forceinline__ unsigned int pack2bf(float lo, float hi) {
  return (unsigned int)f2bf(lo) | ((unsigned int)f2bf(hi) << 16);
}

__device__ __forceinline__ void async_ld16(const void* g, void* l) {
  __builtin_amdgcn_global_load_lds(
      (const __attribute__((address_space(1))) void*)g,
      (__attribute__((address_space(3))) void*)l, 16, 0, 0);
}

// ---------------- x -> bf16 ----------------
__global__ __launch_bounds__(256) void convert_x_kernel(const float* __restrict__ x,
                                                        unsigned short* __restrict__ xb) {
  const size_t i = ((size_t)blockIdx.x * 256 + threadIdx.x) * 4;
  float4 v = *(const float4*)(x + i);
  ushort4 r;
  r.x = f2bf(v.x); r.y = f2bf(v.y); r.z = f2bf(v.z); r.w = f2bf(v.w);
  *(ushort4*)(xb + i) = r;
}

// ---------------- gating compute: fp64 logits, top-2 (NO atomics) ----------------
__global__ __launch_bounds__(256) void gating_kernel(
    const float* __restrict__ x, const float* __restrict__ wg,
    int* __restrict__ tok_e, float* __restrict__ tok_g) {
  const int lane = threadIdx.x & 63;
  const int t = blockIdx.x * 4 + (threadIdx.x >> 6);
  const float* xr = x + (size_t)t * D_DIM;
  double acc[8] = {0, 0, 0, 0, 0, 0, 0, 0};
  for (int d = lane; d < D_DIM; d += 64) {
    double xv = (double)xr[d];
    const float4 w0 = *(const float4*)(wg + d * 8);
    const float4 w1 = *(const float4*)(wg + d * 8 + 4);
    acc[0] += xv * (double)w0.x; acc[1] += xv * (double)w0.y;
    acc[2] += xv * (double)w0.z; acc[3] += xv * (double)w0.w;
    acc[4] += xv * (double)w1.x; acc[5] += xv * (double)w1.y;
    acc[6] += xv * (double)w1.z; acc[7] += xv * (double)w1.w;
  }
#pragma unroll
  for (int e = 0; e < 8; ++e) {
    double v = acc[e];
#pragma unroll
    for (int m = 32; m > 0; m >>= 1) v += __shfl_xor(v, m, 64);
    acc[e] = v;
  }
  if (lane == 0) {
    double b1v = -1e300, b2v = -1e300;
    int i1 = 0, i2 = 0;
#pragma unroll
    for (int e = 0; e < 8; ++e) {
      double v = acc[e];
      if (v > b1v) { b2v = b1v; i2 = i1; b1v = v; i1 = e; }
      else if (v > b2v) { b2v = v; i2 = e; }
    }
    float ex = expf((float)b2v - (float)b1v);
    float den = 1.f + ex;
    tok_e[2 * t] = i1; tok_e[2 * t + 1] = i2;
    tok_g[2 * t] = 1.f / den; tok_g[2 * t + 1] = ex / den;
  }
}

// ---------------- route: single-block counting sort + loss ----------------
__global__ __launch_bounds__(1024) void route_kernel(
    const int* __restrict__ tok_e, const float* __restrict__ tok_g,
    int* __restrict__ tok_p, int* __restrict__ bucket,
    int* __restrict__ counts, int* __restrict__ offs,
    const float* __restrict__ coef, float* __restrict__ loss_out) {
  __shared__ int wavecnt[16][8];
  __shared__ int wavebase[16][8];
  __shared__ int run[8];
  __shared__ float impl[8];
  const int tid = threadIdx.x, lane = tid & 63, wv = tid >> 6;
  if (tid < 8) { run[tid] = 0; impl[tid] = 0.f; }
  __syncthreads();
  for (int c = 0; c < 8; ++c) {
    const int i = c * 1024 + tid;
    const int e = tok_e[i];
    const float g = tok_g[i];
    int rank = 0;
#pragma unroll
    for (int ee = 0; ee < 8; ++ee) {
      unsigned long long m = __ballot(e == ee);
      if (e == ee) rank = __popcll(m & ((1ull << lane) - 1ull));
      float s = (e == ee) ? g : 0.f;
#pragma unroll
      for (int o = 32; o > 0; o >>= 1) s += __shfl_xor(s, o, 64);
      if (lane == 0) {
        wavecnt[wv][ee] = __popcll(m);
        impl[ee] += 0.f;  // touch
        atomicAdd(&impl[ee], s);
      }
    }
    __syncthreads();
    if (tid < 8) {
      int base = run[tid];
      for (int w = 0; w < 16; ++w) { wavebase[w][tid] = base; base += wavecnt[w][tid]; }
      run[tid] = base;
    }
    __syncthreads();
    const int pos = wavebase[wv][e] + rank;
    tok_p[i] = pos;
    bucket[e * B_TOK + pos] = i >> 1;
  }
  __syncthreads();
  if (tid == 0) {
    int o = 0;
    double mi = 0, ml = 0;
    for (int e = 0; e < 8; ++e) {
      counts[e] = run[e]; offs[e] = o; o += run[e];
      mi += (double)impl[e]; ml += (double)run[e];
    }
    offs[8] = o;
    mi *= 0.125; ml *= 0.125;
    double vi = 0, vl = 0;
    for (int e = 0; e < 8; ++e) {
      double di = (double)impl[e] - mi; vi += di * di;
      double dl = (double)run[e]  - ml; vl += dl * dl;
    }
    vi /= 7.0; vl /= 7.0;
    *loss_out = (float)((vi / (mi * mi + 1e-10) + vl / (ml * ml + 1e-10)) * (double)coef[0]);
  }
}

// ---------------- grouped GEMM with fused B transpose+convert ----------------
// C[m][n] (+)= sum_k A[m][k] * W[k_base+k][n_base+n0+n], W fp32 row-major [*][WROW].
// B-tile staged per K-step: 4x float4 fp32 reads (prefetched one step ahead),
// bf16 pack in regs, ds_write into [n][32]-short LDS (same layout as before).
template <int KDIM, int WROW, bool GATHER, bool RELU, bool ACCUM>
__global__ __launch_bounds__(256) void grouped_gemm(
    const unsigned short* __restrict__ A, const float* __restrict__ W,
    size_t wse, int k_base, int n_base,
    const float* __restrict__ bias, int biasN,
    const int* __restrict__ counts, const int* __restrict__ offs,
    const int* __restrict__ bucket, unsigned short* __restrict__ Out, int outN) {
  const int e = blockIdx.z;
  const int n_e = counts[e];
  const int row0 = blockIdx.y * 128;
  if (row0 >= n_e) return;
  const int m_cnt = min(128, n_e - row0);
  const int n0 = blockIdx.x * 128;
  const int slot0 = offs[e] + row0;

  __shared__ unsigned short Alds[128][32];
  __shared__ unsigned short Blds[128][32];
  __shared__ int toklds[128];

  const int tid = threadIdx.x;
  const int lane = tid & 63;
  const int wid = tid >> 6;
  const int q = lane >> 4, l15 = lane & 15;
  const int wm = (wid >> 1) * 64, wn = (wid & 1) * 64;

  if (GATHER) {
    if (tid < 128) toklds[tid] = bucket[e * B_TOK + row0 + min(tid, m_cnt - 1)];
    __syncthreads();
  }
  const int r0 = tid >> 2;
  const int kc = (tid & 3) * 8;
  size_t ga0, ga1;
  if (GATHER) {
    ga0 = (size_t)toklds[r0] * KDIM + kc;
    ga1 = (size_t)toklds[r0 + 64] * KDIM + kc;
  } else {
    ga0 = (size_t)(slot0 + min(r0, m_cnt - 1)) * KDIM + kc;
    ga1 = (size_t)(slot0 + min(r0 + 64, m_cnt - 1)) * KDIM + kc;
  }
  char* aldsw = (char*)Alds + wid * 1024;

  // B staging map: kp = k-pair 0..15 (rows 2kp,2kp+1 of the K-step),
  // nb = n-octet 0..15 (cols nb*8..nb*8+7 of the 128-wide tile).
  const int kp = tid & 15;
  const int nb = tid >> 4;
  const float* wb = W + (size_t)e * wse +
                    ((size_t)(k_base + 2 * kp)) * WROW + n_base + n0 + nb * 8;

  float4 c0, c1, c2, c3;  // current-step B regs
  float4 p0, p1, p2, p3;  // prefetch (next step)
  {  // k0 = 0
    c0 = *(const float4*)(wb);
    c1 = *(const float4*)(wb + 4);
    c2 = *(const float4*)(wb + WROW);
    c3 = *(const float4*)(wb + WROW + 4);
  }

  f32x4 acc[4][4] = {};
  unsigned int* bl = (unsigned int*)Blds;  // [128][16] uints == [128][32] shorts

#pragma unroll 2
  for (int k0 = 0; k0 < KDIM; k0 += 32) {
    // A: async global->LDS (unchanged path)
    async_ld16(A + ga0 + k0, aldsw);
    async_ld16(A + ga1 + k0, aldsw + 4096);
    // B: prefetch next K-step into p-regs
    if (k0 + 32 < KDIM) {
      const float* wn_ = wb + (size_t)(k0 + 32) * WROW;
      p0 = *(const float4*)(wn_);
      p1 = *(const float4*)(wn_ + 4);
      p2 = *(const float4*)(wn_ + WROW);
      p3 = *(const float4*)(wn_ + WROW + 4);
    }
    // B: convert+pack current regs, write to LDS [n][kp]
#pragma unroll
    for (int i = 0; i < 4; ++i) {
      unsigned int lo = pack2bf(((const float*)&c0)[i], ((const float*)&c2)[i]);
      unsigned int hi = pack2bf(((const float*)&c1)[i], ((const float*)&c3)[i]);
      bl[(nb * 8 + i) * 16 + kp] = lo;
      bl[(nb * 8 + 4 + i) * 16 + kp] = hi;
    }
    __syncthreads();  // A vmcnt + B ds_writes drained; tiles ready
    short8 af[4], bfr[4];
#pragma unroll
    for (int mi = 0; mi < 4; ++mi) af[mi] = *(const short8*)&Alds[wm + mi * 16 + l15][q * 8];
#pragma unroll
    for (int ni = 0; ni < 4; ++ni) bfr[ni] = *(const short8*)&Blds[wn + ni * 16 + l15][q * 8];
#pragma unroll
    for (int mi = 0; mi < 4; ++mi)
#pragma unroll
      for (int ni = 0; ni < 4; ++ni)
        acc[mi][ni] = __builtin_amdgcn_mfma_f32_16x16x32_bf16(af[mi], bfr[ni], acc[mi][ni], 0, 0, 0);
    __syncthreads();  // LDS free for next step's writes
    c0 = p0; c1 = p1; c2 = p2; c3 = p3;
  }

  const float* be = bias + (size_t)e * biasN + n_base + n0;
#pragma unroll
  for (int ni = 0; ni < 4; ++ni) {
    const int c = wn + ni * 16 + l15;
    const float bv = ACCUM ? 0.f : be[c];
#pragma unroll
    for (int mi = 0; mi < 4; ++mi) {
      const int rb = wm + mi * 16 + q * 4;
#pragma unroll
      for (int rg = 0; rg < 4; ++rg) {
        const int r = rb + rg;
        if (r < m_cnt) {
          float v = acc[mi][ni][rg] + bv;
          if (RELU) v = fmaxf(v, 0.f);
          unsigned short* op = Out + (size_t)(slot0 + r) * outN + n0 + c;
          if (ACCUM) v += bf2f(*op);
          *op = f2bf(v);
        }
      }
    }
  }
}

// ---------------- combine ----------------
__device__ __forceinline__ float comb1(float a, float b, float g1, float g2) {
  float c = g1 * expf(a) + g2 * expf(b);
  if (c == 0.f) c = 2.220446049250313e-16f;
  return logf(c);
}

__global__ __launch_bounds__(256) void combine_kernel(
    const unsigned short* __restrict__ o_buf, const int* __restrict__ offs,
    const int* __restrict__ tok_e, const int* __restrict__ tok_p,
    const float* __restrict__ tok_g, float* __restrict__ y) {
  const int t = blockIdx.x;
  const int e1 = tok_e[2 * t], e2 = tok_e[2 * t + 1];
  const int s1 = offs[e1] + tok_p[2 * t];
  const int s2 = offs[e2] + tok_p[2 * t + 1];
  const float g1 = tok_g[2 * t], g2 = tok_g[2 * t + 1];
  const int i = threadIdx.x * 4;
  ushort4 a4 = *(const ushort4*)(o_buf + (size_t)s1 * D_DIM + i);
  ushort4 b4 = *(const ushort4*)(o_buf + (size_t)s2 * D_DIM + i);
  float4 r;
  r.x = comb1(bf2f(a4.x), bf2f(b4.x), g1, g2);
  r.y = comb1(bf2f(a4.y), bf2f(b4.y), g1, g2);
  r.z = comb1(bf2f(a4.z), bf2f(b4.z), g1, g2);
  r.w = comb1(bf2f(a4.w), bf2f(b4.w), g1, g2);
  *(float4*)(y + (size_t)t * D_DIM + i) = r;
}

// ---------------- launch ----------------
extern "C" void kernel_launch(void* const* d_in, const int* in_sizes, int n_in,
                              void* d_out, int out_size, void* d_ws, size_t ws_size,
                              hipStream_t stream) {
  const float* x  = (const float*)d_in[0];
  const float* wg = (const float*)d_in[1];
  const float* W1 = (const float*)d_in[2];
  const float* b1 = (const float*)d_in[3];
  const float* W2 = (const float*)d_in[4];
  const float* b2 = (const float*)d_in[5];
  const float* cf = (const float*)d_in[6];
  float* y = (float*)d_out;

  char* w = (char*)d_ws;
  unsigned short* x_bf = (unsigned short*)(w);              // 8,388,608 B
  int*   counts = (int*)(w + 8388608);
  int*   offs   = (int*)(w + 8388672);
  int*   tok_e  = (int*)(w + 8388736);
  int*   tok_p  = (int*)(w + 8421504);
  float* tok_g  = (float*)(w + 8454272);
  int*   bucket = (int*)(w + 8487040);                      // ends 8,618,112
  unsigned short* h_half = (unsigned short*)(w + 42172544); // 33,554,432 B
  unsigned short* o_buf  = (unsigned short*)(w + 75726976); // 16,777,216 B
  if (ws_size < 92504192) return;

  convert_x_kernel<<<4096, 256, 0, stream>>>(x, x_bf);
  gating_kernel<<<1024, 256, 0, stream>>>(x, wg, tok_e, tok_g);
  route_kernel<<<1, 1024, 0, stream>>>(tok_e, tok_g, tok_p, bucket, counts, offs,
                                       cf, y + (size_t)B_TOK * D_DIM);

  for (int p = 0; p < 2; ++p) {
    // GEMM1: A=x_bf [tok][1024], B=W1[e][k=1024][n=4096] cols [p*2048,+2048)
    grouped_gemm<D_DIM, H_DIM, true, true, false>
        <<<dim3(H_HALF / 128, 32, N_EXP), 256, 0, stream>>>(
            x_bf, W1, (size_t)D_DIM * H_DIM, 0, p * H_HALF,
            b1, H_DIM, counts, offs, bucket, h_half, H_HALF);
    // GEMM2: A=h_half [slot][2048], B=W2[e][k=4096][n=1024] rows [p*2048,+2048)
    if (p == 0)
      grouped_gemm<H_HALF, D_DIM, false, false, false>
          <<<dim3(D_DIM / 128, 32, N_EXP), 256, 0, stream>>>(
              h_half, W2, (size_t)H_DIM * D_DIM, p * H_HALF, 0,
              b2, D_DIM, counts, offs, bucket, o_buf, D_DIM);
    else
      grouped_gemm<H_HALF, D_DIM, false, false, true>
          <<<dim3(D_DIM / 128, 32, N_EXP), 256, 0, stream>>>(
              h_half, W2, (size_t)H_DIM * D_DIM, p * H_HALF, 0,
              b2, D_DIM, counts, offs, bucket, o_buf, D_DIM);
  }

  combine_kernel<<<4096, 256, 0, stream>>>(o_buf, offs, tok_e, tok_p, tok_g, y);
}

// Round 8
// 804.892 us; speedup vs baseline: 1.2109x; 1.2109x over previous
//
#include <hip/hip_runtime.h>

// MoE top-2 of 8 experts. B=4096 tokens, D=1024, H=4096.
// Round 11 (= round 10 resubmitted after infra failure): fused B
// transpose+convert with COALESCED staging map: lanes read 512B-contiguous
// W-row runs, pack bf16, ds_write into padded [128][34]-short B LDS
// (writes <=4-way, frag reads conflict-free b32 at 17-uint stride).
// p-split removed: GEMM1 full N=4096, GEMM2 full K=4096, no ACCUM.
// Pipeline: 6 dispatches (was 11).

typedef __attribute__((ext_vector_type(8))) short short8;
typedef __attribute__((ext_vector_type(4))) float f32x4;

#define B_TOK 4096
#define D_DIM 1024
#define H_DIM 4096
#define N_EXP 8

__device__ __forceinline__ unsigned short f2bf(float f) {
  unsigned int u = __float_as_uint(f);
  u += 0x7fffu + ((u >> 16) & 1u);  // RNE
  return (unsigned short)(u >> 16);
}
__device__ __forceinline__ float bf2f(unsigned short s) {
  return __uint_as_float(((unsigned int)s) << 16);
}
__device__ __forceinline__ unsigned int pack2bf(float lo, float hi) {
  return (unsigned int)f2bf(lo) | ((unsigned int)f2bf(hi) << 16);
}

__device__ __forceinline__ void async_ld16(const void* g, void* l) {
  __builtin_amdgcn_global_load_lds(
      (const __attribute__((address_space(1))) void*)g,
      (__attribute__((address_space(3))) void*)l, 16, 0, 0);
}

// ---------------- x -> bf16 ----------------
__global__ __launch_bounds__(256) void convert_x_kernel(const float* __restrict__ x,
                                                        unsigned short* __restrict__ xb) {
  const size_t i = ((size_t)blockIdx.x * 256 + threadIdx.x) * 4;
  float4 v = *(const float4*)(x + i);
  ushort4 r;
  r.x = f2bf(v.x); r.y = f2bf(v.y); r.z = f2bf(v.z); r.w = f2bf(v.w);
  *(ushort4*)(xb + i) = r;
}

// ---------------- gating compute: fp64 logits, top-2 (NO atomics) ----------------
__global__ __launch_bounds__(256) void gating_kernel(
    const float* __restrict__ x, const float* __restrict__ wg,
    int* __restrict__ tok_e, float* __restrict__ tok_g) {
  const int lane = threadIdx.x & 63;
  const int t = blockIdx.x * 4 + (threadIdx.x >> 6);
  const float* xr = x + (size_t)t * D_DIM;
  double acc[8] = {0, 0, 0, 0, 0, 0, 0, 0};
  for (int d = lane; d < D_DIM; d += 64) {
    double xv = (double)xr[d];
    const float4 w0 = *(const float4*)(wg + d * 8);
    const float4 w1 = *(const float4*)(wg + d * 8 + 4);
    acc[0] += xv * (double)w0.x; acc[1] += xv * (double)w0.y;
    acc[2] += xv * (double)w0.z; acc[3] += xv * (double)w0.w;
    acc[4] += xv * (double)w1.x; acc[5] += xv * (double)w1.y;
    acc[6] += xv * (double)w1.z; acc[7] += xv * (double)w1.w;
  }
#pragma unroll
  for (int e = 0; e < 8; ++e) {
    double v = acc[e];
#pragma unroll
    for (int m = 32; m > 0; m >>= 1) v += __shfl_xor(v, m, 64);
    acc[e] = v;
  }
  if (lane == 0) {
    double b1v = -1e300, b2v = -1e300;
    int i1 = 0, i2 = 0;
#pragma unroll
    for (int e = 0; e < 8; ++e) {
      double v = acc[e];
      if (v > b1v) { b2v = b1v; i2 = i1; b1v = v; i1 = e; }
      else if (v > b2v) { b2v = v; i2 = e; }
    }
    float ex = expf((float)b2v - (float)b1v);
    float den = 1.f + ex;
    tok_e[2 * t] = i1; tok_e[2 * t + 1] = i2;
    tok_g[2 * t] = 1.f / den; tok_g[2 * t + 1] = ex / den;
  }
}

// ---------------- route: single-block counting sort + loss ----------------
__global__ __launch_bounds__(1024) void route_kernel(
    const int* __restrict__ tok_e, const float* __restrict__ tok_g,
    int* __restrict__ tok_p, int* __restrict__ bucket,
    int* __restrict__ counts, int* __restrict__ offs,
    const float* __restrict__ coef, float* __restrict__ loss_out) {
  __shared__ int wavecnt[16][8];
  __shared__ int wavebase[16][8];
  __shared__ int run[8];
  __shared__ float impl[8];
  const int tid = threadIdx.x, lane = tid & 63, wv = tid >> 6;
  if (tid < 8) { run[tid] = 0; impl[tid] = 0.f; }
  __syncthreads();
  for (int c = 0; c < 8; ++c) {
    const int i = c * 1024 + tid;
    const int e = tok_e[i];
    const float g = tok_g[i];
    int rank = 0;
#pragma unroll
    for (int ee = 0; ee < 8; ++ee) {
      unsigned long long m = __ballot(e == ee);
      if (e == ee) rank = __popcll(m & ((1ull << lane) - 1ull));
      float s = (e == ee) ? g : 0.f;
#pragma unroll
      for (int o = 32; o > 0; o >>= 1) s += __shfl_xor(s, o, 64);
      if (lane == 0) {
        wavecnt[wv][ee] = __popcll(m);
        impl[ee] += 0.f;  // touch
        atomicAdd(&impl[ee], s);
      }
    }
    __syncthreads();
    if (tid < 8) {
      int base = run[tid];
      for (int w = 0; w < 16; ++w) { wavebase[w][tid] = base; base += wavecnt[w][tid]; }
      run[tid] = base;
    }
    __syncthreads();
    const int pos = wavebase[wv][e] + rank;
    tok_p[i] = pos;
    bucket[e * B_TOK + pos] = i >> 1;
  }
  __syncthreads();
  if (tid == 0) {
    int o = 0;
    double mi = 0, ml = 0;
    for (int e = 0; e < 8; ++e) {
      counts[e] = run[e]; offs[e] = o; o += run[e];
      mi += (double)impl[e]; ml += (double)run[e];
    }
    offs[8] = o;
    mi *= 0.125; ml *= 0.125;
    double vi = 0, vl = 0;
    for (int e = 0; e < 8; ++e) {
      double di = (double)impl[e] - mi; vi += di * di;
      double dl = (double)run[e]  - ml; vl += dl * dl;
    }
    vi /= 7.0; vl /= 7.0;
    *loss_out = (float)((vi / (mi * mi + 1e-10) + vl / (ml * ml + 1e-10)) * (double)coef[0]);
  }
}

// ---------------- grouped GEMM, fused B transpose+convert (coalesced) ----------------
// C[m][n] = relu?(sum_k A[m][k] * W[k][n] + bias[n]); W fp32 row-major [KDIM][WROW].
// B K-step staging: thread (p=k-pair, c=col-group) reads rows 2p,2p+1 at cols 4c..4c+3
// (lanes 0..31 cover 512B contiguous), packs bf16 pairs, writes Blds[n][34-short rows].
template <int KDIM, int WROW, bool GATHER, bool RELU>
__global__ __launch_bounds__(256) void grouped_gemm(
    const unsigned short* __restrict__ A, const float* __restrict__ W,
    const float* __restrict__ bias,
    const int* __restrict__ counts, const int* __restrict__ offs,
    const int* __restrict__ bucket, unsigned short* __restrict__ Out, int outN) {
  const int e = blockIdx.z;
  const int n_e = counts[e];
  const int row0 = blockIdx.y * 128;
  if (row0 >= n_e) return;
  const int m_cnt = min(128, n_e - row0);
  const int n0 = blockIdx.x * 128;
  const int slot0 = offs[e] + row0;

  __shared__ unsigned short Alds[128][32];   // 8 KiB (A: global_load_lds, unchanged)
  __shared__ unsigned short Blds[128][34];   // 8.5 KiB, padded: 17-uint rows
  __shared__ int toklds[GATHER ? 128 : 1];

  const int tid = threadIdx.x;
  const int lane = tid & 63;
  const int wid = tid >> 6;
  const int q = lane >> 4, l15 = lane & 15;
  const int wm = (wid >> 1) * 64, wn = (wid & 1) * 64;

  if (GATHER) {
    if (tid < 128) toklds[tid] = bucket[e * B_TOK + row0 + min(tid, m_cnt - 1)];
    __syncthreads();
  }
  const int r0 = tid >> 2;
  const int kc = (tid & 3) * 8;
  size_t ga0, ga1;
  if (GATHER) {
    ga0 = (size_t)toklds[r0] * KDIM + kc;
    ga1 = (size_t)toklds[r0 + 64] * KDIM + kc;
  } else {
    ga0 = (size_t)(slot0 + min(r0, m_cnt - 1)) * KDIM + kc;
    ga1 = (size_t)(slot0 + min(r0 + 64, m_cnt - 1)) * KDIM + kc;
  }
  char* aldsw = (char*)Alds + wid * 1024;

  // --- B staging map (coalesced) ---
  // round 0: p = tid>>5 (k-pair 0..7), round 1: p+8; c = tid&31 (col-group).
  const int pA = tid >> 5;       // 0..7
  const int pB = pA + 8;         // 8..15
  const int cg = tid & 31;
  const float* wbase = W + (size_t)e * KDIM * WROW + n0 + 4 * cg;

  auto loadB = [&](int k0, float4& a0, float4& a1, float4& b0, float4& b1) {
    const float* w0 = wbase + (size_t)(k0 + 2 * pA) * WROW;
    const float* w1 = wbase + (size_t)(k0 + 2 * pB) * WROW;
    a0 = *(const float4*)w0;
    a1 = *(const float4*)(w0 + WROW);
    b0 = *(const float4*)w1;
    b1 = *(const float4*)(w1 + WROW);
  };

  float4 ca0, ca1, cb0, cb1;  // current K-step B regs
  float4 pa0, pa1, pb0, pb1;  // prefetch (next K-step)
  loadB(0, ca0, ca1, cb0, cb1);

  f32x4 acc[4][4] = {};
  unsigned int* bl = (unsigned int*)Blds;  // 17 uints per n-row

#pragma unroll 2
  for (int k0 = 0; k0 < KDIM; k0 += 32) {
    // A: async global->LDS (proven path)
    async_ld16(A + ga0 + k0, aldsw);
    async_ld16(A + ga1 + k0, aldsw + 4096);
    // B: prefetch next K-step
    if (k0 + 32 < KDIM) loadB(k0 + 32, pa0, pa1, pb0, pb1);
    // B: pack current, write LDS [n][k-pair] (<=4-way conflicts)
#pragma unroll
    for (int i = 0; i < 4; ++i) {
      bl[(4 * cg + i) * 17 + pA] = pack2bf(((const float*)&ca0)[i], ((const float*)&ca1)[i]);
      bl[(4 * cg + i) * 17 + pB] = pack2bf(((const float*)&cb0)[i], ((const float*)&cb1)[i]);
    }
    __syncthreads();  // A vmcnt + B ds_writes drained
    short8 af[4], bfr[4];
#pragma unroll
    for (int mi = 0; mi < 4; ++mi) af[mi] = *(const short8*)&Alds[wm + mi * 16 + l15][q * 8];
#pragma unroll
    for (int ni = 0; ni < 4; ++ni) {
      const unsigned int* bp = bl + (wn + ni * 16 + l15) * 17 + q * 4;
      union { unsigned int u[4]; short8 s; } bu;
      bu.u[0] = bp[0]; bu.u[1] = bp[1]; bu.u[2] = bp[2]; bu.u[3] = bp[3];
      bfr[ni] = bu.s;
    }
#pragma unroll
    for (int mi = 0; mi < 4; ++mi)
#pragma unroll
      for (int ni = 0; ni < 4; ++ni)
        acc[mi][ni] = __builtin_amdgcn_mfma_f32_16x16x32_bf16(af[mi], bfr[ni], acc[mi][ni], 0, 0, 0);
    __syncthreads();  // LDS free for next step
    ca0 = pa0; ca1 = pa1; cb0 = pb0; cb1 = pb1;
  }

  const float* be = bias + (size_t)e * outN + n0;
#pragma unroll
  for (int ni = 0; ni < 4; ++ni) {
    const int c = wn + ni * 16 + l15;
    const float bv = be[c];
#pragma unroll
    for (int mi = 0; mi < 4; ++mi) {
      const int rb = wm + mi * 16 + q * 4;
#pragma unroll
      for (int rg = 0; rg < 4; ++rg) {
        const int r = rb + rg;
        if (r < m_cnt) {
          float v = acc[mi][ni][rg] + bv;
          if (RELU) v = fmaxf(v, 0.f);
          Out[(size_t)(slot0 + r) * outN + n0 + c] = f2bf(v);
        }
      }
    }
  }
}

// ---------------- combine ----------------
__device__ __forceinline__ float comb1(float a, float b, float g1, float g2) {
  float c = g1 * expf(a) + g2 * expf(b);
  if (c == 0.f) c = 2.220446049250313e-16f;
  return logf(c);
}

__global__ __launch_bounds__(256) void combine_kernel(
    const unsigned short* __restrict__ o_buf, const int* __restrict__ offs,
    const int* __restrict__ tok_e, const int* __restrict__ tok_p,
    const float* __restrict__ tok_g, float* __restrict__ y) {
  const int t = blockIdx.x;
  const int e1 = tok_e[2 * t], e2 = tok_e[2 * t + 1];
  const int s1 = offs[e1] + tok_p[2 * t];
  const int s2 = offs[e2] + tok_p[2 * t + 1];
  const float g1 = tok_g[2 * t], g2 = tok_g[2 * t + 1];
  const int i = threadIdx.x * 4;
  ushort4 a4 = *(const ushort4*)(o_buf + (size_t)s1 * D_DIM + i);
  ushort4 b4 = *(const ushort4*)(o_buf + (size_t)s2 * D_DIM + i);
  float4 r;
  r.x = comb1(bf2f(a4.x), bf2f(b4.x), g1, g2);
  r.y = comb1(bf2f(a4.y), bf2f(b4.y), g1, g2);
  r.z = comb1(bf2f(a4.z), bf2f(b4.z), g1, g2);
  r.w = comb1(bf2f(a4.w), bf2f(b4.w), g1, g2);
  *(float4*)(y + (size_t)t * D_DIM + i) = r;
}

// ---------------- launch ----------------
extern "C" void kernel_launch(void* const* d_in, const int* in_sizes, int n_in,
                              void* d_out, int out_size, void* d_ws, size_t ws_size,
                              hipStream_t stream) {
  const float* x  = (const float*)d_in[0];
  const float* wg = (const float*)d_in[1];
  const float* W1 = (const float*)d_in[2];
  const float* b1 = (const float*)d_in[3];
  const float* W2 = (const float*)d_in[4];
  const float* b2 = (const float*)d_in[5];
  const float* cf = (const float*)d_in[6];
  float* y = (float*)d_out;

  char* w = (char*)d_ws;
  unsigned short* x_bf = (unsigned short*)(w);              // 8,388,608 B
  int*   counts = (int*)(w + 8388608);
  int*   offs   = (int*)(w + 8388672);
  int*   tok_e  = (int*)(w + 8388736);
  int*   tok_p  = (int*)(w + 8421504);
  float* tok_g  = (float*)(w + 8454272);
  int*   bucket = (int*)(w + 8487040);                      // ends 8,618,112
  unsigned short* h     = (unsigned short*)(w + 8618112);   // 67,108,864 B -> 75,726,976
  unsigned short* o_buf = (unsigned short*)(w + 75726976);  // 16,777,216 B -> 92,504,192
  if (ws_size < 92504192) return;

  convert_x_kernel<<<4096, 256, 0, stream>>>(x, x_bf);
  gating_kernel<<<1024, 256, 0, stream>>>(x, wg, tok_e, tok_g);
  route_kernel<<<1, 1024, 0, stream>>>(tok_e, tok_g, tok_p, bucket, counts, offs,
                                       cf, y + (size_t)B_TOK * D_DIM);

  // GEMM1: A=x_bf [tok][1024], B=W1[e][1024][4096], out h [slot][4096], ReLU+bias
  grouped_gemm<D_DIM, H_DIM, true, true>
      <<<dim3(H_DIM / 128, 32, N_EXP), 256, 0, stream>>>(
          x_bf, W1, b1, counts, offs, bucket, h, H_DIM);
  // GEMM2: A=h [slot][4096], B=W2[e][4096][1024], out o_buf [slot][1024], bias
  grouped_gemm<H_DIM, D_DIM, false, false>
      <<<dim3(D_DIM / 128, 32, N_EXP), 256, 0, stream>>>(
          h, W2, b2, counts, offs, bucket, o_buf, D_DIM);

  combine_kernel<<<4096, 256, 0, stream>>>(o_buf, offs, tok_e, tok_p, tok_g, y);
}